// Round 1
// baseline (1221.555 us; speedup 1.0000x reference)
//
#include <hip/hip_runtime.h>

#define N_NODES 100000
#define N_EDGES 1600000
#define F_IN    501
#define H1      8
#define C1      8
#define D1      64   // H1*C1
#define NCLS    40

__device__ __forceinline__ float lrelu(float x) { return x > 0.f ? x : 0.2f * x; }

// ---------------------------------------------------------------------------
// GEMM1: xh1[N,64] = x[N,501] @ W1[501,64]   (fp32, LDS-tiled 64x64, BK=32)
// ---------------------------------------------------------------------------
__global__ __launch_bounds__(256) void gemm1(const float* __restrict__ x,
                                             const float* __restrict__ W1,
                                             float* __restrict__ xh1) {
    __shared__ float xs[32][68];   // [k][m], row stride 272B (16B aligned)
    __shared__ float ws[32][64];   // [k][n]
    const int tid  = threadIdx.x;
    const int row0 = blockIdx.x * 64;
    const int ty   = tid >> 4;     // 0..15 (row group)
    const int tx   = tid & 15;     // 0..15 (col group)

    float acc[4][4] = {};

    for (int k0 = 0; k0 < F_IN; k0 += 32) {
        // load x tile: 64 rows x 32 k  (coalesced: 8 rows x 32 cols per instr)
        {
            #pragma unroll
            for (int i = 0; i < 8; ++i) {
                int e = tid + i * 256;        // 0..2047
                int r = e >> 5;               // 0..63
                int c = e & 31;               // 0..31
                int grow = row0 + r;
                int k = k0 + c;
                float v = 0.f;
                if (grow < N_NODES && k < F_IN) v = x[(size_t)grow * F_IN + k];
                xs[c][r] = v;                 // transposed store
            }
        }
        // load W tile: 32 k x 64 n
        {
            #pragma unroll
            for (int i = 0; i < 8; ++i) {
                int e = tid + i * 256;        // 0..2047
                int kk = e >> 6;              // 0..31
                int c  = e & 63;              // 0..63
                int k = k0 + kk;
                ws[kk][c] = (k < F_IN) ? W1[(size_t)k * D1 + c] : 0.f;
            }
        }
        __syncthreads();

        #pragma unroll
        for (int kk = 0; kk < 32; ++kk) {
            const float4 av = *reinterpret_cast<const float4*>(&xs[kk][ty * 4]);
            const float4 bv = *reinterpret_cast<const float4*>(&ws[kk][tx * 4]);
            float a4[4] = {av.x, av.y, av.z, av.w};
            float b4[4] = {bv.x, bv.y, bv.z, bv.w};
            #pragma unroll
            for (int i = 0; i < 4; ++i)
                #pragma unroll
                for (int j = 0; j < 4; ++j)
                    acc[i][j] = fmaf(a4[i], b4[j], acc[i][j]);
        }
        __syncthreads();
    }

    #pragma unroll
    for (int i = 0; i < 4; ++i) {
        int row = row0 + ty * 4 + i;
        if (row < N_NODES) {
            float4 v = make_float4(acc[i][0], acc[i][1], acc[i][2], acc[i][3]);
            *reinterpret_cast<float4*>(&xh1[(size_t)row * D1 + tx * 4]) = v;
        }
    }
}

// ---------------------------------------------------------------------------
// A1: per-(node,head) attention coefficients for layer 1
// ---------------------------------------------------------------------------
__global__ void a1k(const float* __restrict__ xh1,
                    const float* __restrict__ att_s, const float* __restrict__ att_d,
                    const int* __restrict__ idxp,
                    float* __restrict__ a_src, float* __restrict__ a_dst) {
    int gid = blockIdx.x * blockDim.x + threadIdx.x;
    if (gid >= N_NODES * H1) return;
    int n = gid >> 3, h = gid & 7;
    float sign = (idxp[0] == 1) ? -1.f : 1.f;
    const float* xr = xh1 + (size_t)n * D1 + h * C1;
    float ss = 0.f, sd = 0.f;
    #pragma unroll
    for (int c = 0; c < C1; ++c) {
        float v = xr[c];
        ss += v * att_s[h * C1 + c];
        sd += v * att_d[h * C1 + c];
    }
    a_src[gid] = sign * ss;
    a_dst[gid] = sign * sd;
}

// ---------------------------------------------------------------------------
// E1: edge pass layer 1. 64 threads per edge (one per output channel).
// Accumulates unnormalized weighted features + denominator with atomics.
// ---------------------------------------------------------------------------
__global__ __launch_bounds__(256) void e1k(const int* __restrict__ ei,
                                           const float* __restrict__ xh1,
                                           const float* __restrict__ a_src,
                                           const float* __restrict__ a_dst,
                                           float* __restrict__ agg,
                                           float* __restrict__ denom) {
    int gid = blockIdx.x * 256 + threadIdx.x;   // < 1.6M*64 = 102.4M, fits int
    if (gid >= N_EDGES * D1) return;
    int eid = gid >> 6;
    int c   = gid & 63;
    int h   = c >> 3;
    int s = ei[eid];
    int d = ei[N_EDGES + eid];
    float e = __expf(lrelu(a_src[s * H1 + h] + a_dst[d * H1 + h]));
    atomicAdd(&agg[(size_t)d * D1 + c], e * xh1[(size_t)s * D1 + c]);
    if ((c & 7) == 0) atomicAdd(&denom[d * H1 + h], e);
}

// ---------------------------------------------------------------------------
// N1: add self-loop, normalize, ELU. Writes h in place of agg.
// ---------------------------------------------------------------------------
__global__ void n1k(const float* __restrict__ xh1,
                    const float* __restrict__ a_src, const float* __restrict__ a_dst,
                    const float* __restrict__ denom,
                    float* __restrict__ agg /* in: agg, out: h */) {
    int gid = blockIdx.x * blockDim.x + threadIdx.x;
    if (gid >= N_NODES * D1) return;
    int n = gid >> 6, c = gid & 63, h = c >> 3;
    float es = __expf(lrelu(a_src[n * H1 + h] + a_dst[n * H1 + h]));
    float v = (agg[gid] + es * xh1[gid]) / (denom[n * H1 + h] + es + 1e-16f);
    agg[gid] = v > 0.f ? v : (__expf(v) - 1.f);
}

// ---------------------------------------------------------------------------
// GEMM2: xh2[N,40] = h[N,64] @ W2[64,40]  (small K, naive per-output)
// ---------------------------------------------------------------------------
__global__ void gemm2(const float* __restrict__ h,
                      const float* __restrict__ W2,
                      float* __restrict__ xh2) {
    int gid = blockIdx.x * blockDim.x + threadIdx.x;
    if (gid >= N_NODES * NCLS) return;
    int n = gid / NCLS, c = gid % NCLS;
    const float* hr = h + (size_t)n * D1;
    float s = 0.f;
    #pragma unroll
    for (int k = 0; k < D1; ++k) s = fmaf(hr[k], W2[k * NCLS + c], s);
    xh2[gid] = s;
}

// ---------------------------------------------------------------------------
// A2: per-node attention coefficients for layer 2 (1 head, 40 ch)
// ---------------------------------------------------------------------------
__global__ void a2k(const float* __restrict__ xh2,
                    const float* __restrict__ att_s2, const float* __restrict__ att_d2,
                    const int* __restrict__ idxp,
                    float* __restrict__ a_src2, float* __restrict__ a_dst2) {
    int n = blockIdx.x * blockDim.x + threadIdx.x;
    if (n >= N_NODES) return;
    float sign = (idxp[0] == 1) ? -1.f : 1.f;
    float ss = 0.f, sd = 0.f;
    #pragma unroll
    for (int c = 0; c < NCLS; ++c) {
        float v = xh2[(size_t)n * NCLS + c];
        ss += v * att_s2[c];
        sd += v * att_d2[c];
    }
    a_src2[n] = sign * ss;
    a_dst2[n] = sign * sd;
}

// ---------------------------------------------------------------------------
// E2: edge pass layer 2. 64 threads per edge, 40 active channels.
// ---------------------------------------------------------------------------
__global__ __launch_bounds__(256) void e2k(const int* __restrict__ ei,
                                           const float* __restrict__ xh2,
                                           const float* __restrict__ a_src2,
                                           const float* __restrict__ a_dst2,
                                           float* __restrict__ agg2,
                                           float* __restrict__ denom2) {
    int gid = blockIdx.x * 256 + threadIdx.x;
    if (gid >= N_EDGES * 64) return;
    int eid = gid >> 6;
    int c   = gid & 63;
    int s = ei[eid];
    int d = ei[N_EDGES + eid];
    float e = __expf(lrelu(a_src2[s] + a_dst2[d]));
    if (c < NCLS) atomicAdd(&agg2[(size_t)d * NCLS + c], e * xh2[(size_t)s * NCLS + c]);
    if (c == 0)   atomicAdd(&denom2[d], e);
}

// ---------------------------------------------------------------------------
// N2: add self-loop, normalize, + bias -> d_out
// ---------------------------------------------------------------------------
__global__ void n2k(const float* __restrict__ xh2,
                    const float* __restrict__ a_src2, const float* __restrict__ a_dst2,
                    const float* __restrict__ denom2, const float* __restrict__ agg2,
                    const float* __restrict__ bias2, float* __restrict__ out) {
    int gid = blockIdx.x * blockDim.x + threadIdx.x;
    if (gid >= N_NODES * NCLS) return;
    int n = gid / NCLS, c = gid % NCLS;
    float es = __expf(lrelu(a_src2[n] + a_dst2[n]));
    out[gid] = (agg2[gid] + es * xh2[gid]) / (denom2[n] + es + 1e-16f) + bias2[c];
}

// ---------------------------------------------------------------------------
extern "C" void kernel_launch(void* const* d_in, const int* in_sizes, int n_in,
                              void* d_out, int out_size, void* d_ws, size_t ws_size,
                              hipStream_t stream) {
    const float* x    = (const float*)d_in[0];
    const float* W1   = (const float*)d_in[1];
    const float* as1w = (const float*)d_in[2];
    const float* ad1w = (const float*)d_in[3];
    const float* W2   = (const float*)d_in[4];
    const float* as2w = (const float*)d_in[5];
    const float* ad2w = (const float*)d_in[6];
    const float* b2   = (const float*)d_in[7];
    const int*   ei   = (const int*)d_in[8];
    const int*   idxp = (const int*)d_in[9];
    float* out = (float*)d_out;

    // workspace layout (floats)
    float* ws   = (float*)d_ws;
    float* B0   = ws;                         // xh1 [N*64], later xh2 [N*40]
    float* B1   = B0 + (size_t)N_NODES * D1;  // agg1 -> h -> agg2
    float* as1  = B1 + (size_t)N_NODES * D1;  // [N*8]
    float* ad1  = as1 + (size_t)N_NODES * H1;
    float* dn1  = ad1 + (size_t)N_NODES * H1;
    float* as2  = dn1 + (size_t)N_NODES * H1; // [N]
    float* ad2  = as2 + N_NODES;
    float* dn2  = ad2 + N_NODES;

    // zero agg1 + denom1
    hipMemsetAsync(B1,  0, (size_t)N_NODES * D1 * sizeof(float), stream);
    hipMemsetAsync(dn1, 0, (size_t)N_NODES * H1 * sizeof(float), stream);

    gemm1<<<(N_NODES + 63) / 64, 256, 0, stream>>>(x, W1, B0);
    a1k<<<(N_NODES * H1 + 255) / 256, 256, 0, stream>>>(B0, as1w, ad1w, idxp, as1, ad1);
    e1k<<<(N_EDGES * 64) / 256, 256, 0, stream>>>(ei, B0, as1, ad1, B1, dn1);
    n1k<<<(N_NODES * D1 + 255) / 256, 256, 0, stream>>>(B0, as1, ad1, dn1, B1);
    gemm2<<<(N_NODES * NCLS + 255) / 256, 256, 0, stream>>>(B1, W2, B0);
    a2k<<<(N_NODES + 255) / 256, 256, 0, stream>>>(B0, as2w, ad2w, idxp, as2, ad2);

    // zero agg2 + denom2 (B1 reused; must be after gemm2 consumed h)
    hipMemsetAsync(B1,  0, (size_t)N_NODES * NCLS * sizeof(float), stream);
    hipMemsetAsync(dn2, 0, (size_t)N_NODES * sizeof(float), stream);

    e2k<<<(N_EDGES * 64) / 256, 256, 0, stream>>>(ei, B0, as2, ad2, B1, dn2);
    n2k<<<(N_NODES * NCLS + 255) / 256, 256, 0, stream>>>(B0, as2, ad2, dn2, B1, b2, out);
}

// Round 2
// 899.986 us; speedup vs baseline: 1.3573x; 1.3573x over previous
//
#include <hip/hip_runtime.h>

#define N_NODES 100000
#define N_EDGES 1600000
#define F_IN    501
#define H1      8
#define C1      8
#define D1      64   // H1*C1
#define NCLS    40

__device__ __forceinline__ float lrelu(float x) { return x > 0.f ? x : 0.2f * x; }

// ---------------------------------------------------------------------------
// GEMM1: xh1[N,64] = x[N,501] @ W1[501,64]   (fp32, LDS-tiled 64x64, BK=32)
// ---------------------------------------------------------------------------
__global__ __launch_bounds__(256) void gemm1(const float* __restrict__ x,
                                             const float* __restrict__ W1,
                                             float* __restrict__ xh1) {
    __shared__ float xs[32][68];
    __shared__ float ws[32][64];
    const int tid  = threadIdx.x;
    const int row0 = blockIdx.x * 64;
    const int ty   = tid >> 4;
    const int tx   = tid & 15;

    float acc[4][4] = {};

    for (int k0 = 0; k0 < F_IN; k0 += 32) {
        #pragma unroll
        for (int i = 0; i < 8; ++i) {
            int e = tid + i * 256;
            int r = e >> 5, c = e & 31;
            int grow = row0 + r, k = k0 + c;
            float v = 0.f;
            if (grow < N_NODES && k < F_IN) v = x[(size_t)grow * F_IN + k];
            xs[c][r] = v;
        }
        #pragma unroll
        for (int i = 0; i < 8; ++i) {
            int e = tid + i * 256;
            int kk = e >> 6, c = e & 63;
            int k = k0 + kk;
            ws[kk][c] = (k < F_IN) ? W1[(size_t)k * D1 + c] : 0.f;
        }
        __syncthreads();

        #pragma unroll
        for (int kk = 0; kk < 32; ++kk) {
            const float4 av = *reinterpret_cast<const float4*>(&xs[kk][ty * 4]);
            const float4 bv = *reinterpret_cast<const float4*>(&ws[kk][tx * 4]);
            float a4[4] = {av.x, av.y, av.z, av.w};
            float b4[4] = {bv.x, bv.y, bv.z, bv.w};
            #pragma unroll
            for (int i = 0; i < 4; ++i)
                #pragma unroll
                for (int j = 0; j < 4; ++j)
                    acc[i][j] = fmaf(a4[i], b4[j], acc[i][j]);
        }
        __syncthreads();
    }

    #pragma unroll
    for (int i = 0; i < 4; ++i) {
        int row = row0 + ty * 4 + i;
        if (row < N_NODES) {
            float4 v = make_float4(acc[i][0], acc[i][1], acc[i][2], acc[i][3]);
            *reinterpret_cast<float4*>(&xh1[(size_t)row * D1 + tx * 4]) = v;
        }
    }
}

// ---------------------------------------------------------------------------
// A1: per-(node,head) attention coefficients for layer 1
// ---------------------------------------------------------------------------
__global__ void a1k(const float* __restrict__ xh1,
                    const float* __restrict__ att_s, const float* __restrict__ att_d,
                    const int* __restrict__ idxp,
                    float* __restrict__ a_src, float* __restrict__ a_dst) {
    int gid = blockIdx.x * blockDim.x + threadIdx.x;
    if (gid >= N_NODES * H1) return;
    int n = gid >> 3, h = gid & 7;
    float sign = (idxp[0] == 1) ? -1.f : 1.f;
    const float* xr = xh1 + (size_t)n * D1 + h * C1;
    float ss = 0.f, sd = 0.f;
    #pragma unroll
    for (int c = 0; c < C1; ++c) {
        float v = xr[c];
        ss += v * att_s[h * C1 + c];
        sd += v * att_d[h * C1 + c];
    }
    a_src[gid] = sign * ss;
    a_dst[gid] = sign * sd;
}

// ---------------------------------------------------------------------------
// CSR build: histogram -> scan -> scatter
// ---------------------------------------------------------------------------
__global__ void k_hist(const int* __restrict__ ei, int* __restrict__ cnt) {
    int e = blockIdx.x * blockDim.x + threadIdx.x;
    if (e >= N_EDGES) return;
    atomicAdd(&cnt[ei[N_EDGES + e]], 1);
}

// block = 256 threads, 1024 elements per block
__global__ __launch_bounds__(256) void k_scan1(const int* __restrict__ cnt,
                                               int* __restrict__ pre,
                                               int* __restrict__ bsum) {
    __shared__ int s[256];
    int t = threadIdx.x;
    int base = blockIdx.x * 1024 + t * 4;
    int v[4], sum = 0;
    #pragma unroll
    for (int i = 0; i < 4; ++i) {
        v[i] = (base + i < N_NODES) ? cnt[base + i] : 0;
        sum += v[i];
    }
    s[t] = sum;
    __syncthreads();
    for (int off = 1; off < 256; off <<= 1) {
        int x = 0;
        if (t >= off) x = s[t - off];
        __syncthreads();
        if (t >= off) s[t] += x;
        __syncthreads();
    }
    int run = s[t] - sum;                 // exclusive prefix of this thread
    if (t == 255) bsum[blockIdx.x] = s[255];
    #pragma unroll
    for (int i = 0; i < 4; ++i) {
        if (base + i < N_NODES) pre[base + i] = run;
        run += v[i];
    }
}

__global__ void k_scan2(int* __restrict__ bsum, int nb) {
    __shared__ int s[128];
    int t = threadIdx.x;
    int v = (t < nb) ? bsum[t] : 0;
    s[t] = v;
    __syncthreads();
    for (int off = 1; off < 128; off <<= 1) {
        int x = 0;
        if (t >= off) x = s[t - off];
        __syncthreads();
        if (t >= off) s[t] += x;
        __syncthreads();
    }
    if (t < nb) bsum[t] = s[t] - v;       // exclusive
}

__global__ void k_scan3(const int* __restrict__ pre, const int* __restrict__ bsum,
                        int* __restrict__ rowptr, int* __restrict__ wofs) {
    int i = blockIdx.x * blockDim.x + threadIdx.x;
    if (i < N_NODES) {
        int r = pre[i] + bsum[i >> 10];
        rowptr[i] = r;
        wofs[i]   = r;
    } else if (i == N_NODES) {
        rowptr[N_NODES] = N_EDGES;
    }
}

__global__ void k_scatter(const int* __restrict__ ei, int* __restrict__ wofs,
                          int* __restrict__ ssrc) {
    int e = blockIdx.x * blockDim.x + threadIdx.x;
    if (e >= N_EDGES) return;
    int s = ei[e], d = ei[N_EDGES + e];
    int p = atomicAdd(&wofs[d], 1);
    ssrc[p] = s;
}

// ---------------------------------------------------------------------------
// AGG1: one wave per destination node; lane = output channel.
// Fuses softmax (unnormalized), self-loop, normalize, ELU.
// ---------------------------------------------------------------------------
__global__ __launch_bounds__(256) void agg1(const int* __restrict__ rowptr,
                                            const int* __restrict__ ssrc,
                                            const float* __restrict__ xh1,
                                            const float* __restrict__ a_src,
                                            const float* __restrict__ a_dst,
                                            float* __restrict__ h) {
    int wid  = (blockIdx.x * 256 + threadIdx.x) >> 6;
    int lane = threadIdx.x & 63;
    if (wid >= N_NODES) return;
    const int d = wid, c = lane, hh = lane >> 3;

    const float adh = a_dst[d * H1 + hh];
    // self loop
    float e0  = __expf(lrelu(a_src[d * H1 + hh] + adh));
    float acc = e0 * xh1[(size_t)d * D1 + c];
    float den = e0;

    const int beg = rowptr[d], end = rowptr[d + 1];
    for (int p = beg; p < end; ++p) {
        int s = ssrc[p];
        float e = __expf(lrelu(a_src[s * H1 + hh] + adh));
        acc = fmaf(e, xh1[(size_t)s * D1 + c], acc);
        den += e;
    }
    float v = acc / (den + 1e-16f);
    h[(size_t)d * D1 + c] = v > 0.f ? v : (__expf(v) - 1.f);
}

// ---------------------------------------------------------------------------
// GEMM2: xh2[N,40] = h[N,64] @ W2[64,40]
// ---------------------------------------------------------------------------
__global__ void gemm2(const float* __restrict__ h,
                      const float* __restrict__ W2,
                      float* __restrict__ xh2) {
    int gid = blockIdx.x * blockDim.x + threadIdx.x;
    if (gid >= N_NODES * NCLS) return;
    int n = gid / NCLS, c = gid % NCLS;
    const float* hr = h + (size_t)n * D1;
    float s = 0.f;
    #pragma unroll
    for (int k = 0; k < D1; ++k) s = fmaf(hr[k], W2[k * NCLS + c], s);
    xh2[gid] = s;
}

// ---------------------------------------------------------------------------
// A2: per-node attention coefficients for layer 2
// ---------------------------------------------------------------------------
__global__ void a2k(const float* __restrict__ xh2,
                    const float* __restrict__ att_s2, const float* __restrict__ att_d2,
                    const int* __restrict__ idxp,
                    float* __restrict__ a_src2, float* __restrict__ a_dst2) {
    int n = blockIdx.x * blockDim.x + threadIdx.x;
    if (n >= N_NODES) return;
    float sign = (idxp[0] == 1) ? -1.f : 1.f;
    float ss = 0.f, sd = 0.f;
    #pragma unroll
    for (int c = 0; c < NCLS; ++c) {
        float v = xh2[(size_t)n * NCLS + c];
        ss += v * att_s2[c];
        sd += v * att_d2[c];
    }
    a_src2[n] = sign * ss;
    a_dst2[n] = sign * sd;
}

// ---------------------------------------------------------------------------
// AGG2: one wave per destination node; lanes 0..39 = channels. Fused bias.
// ---------------------------------------------------------------------------
__global__ __launch_bounds__(256) void agg2(const int* __restrict__ rowptr,
                                            const int* __restrict__ ssrc,
                                            const float* __restrict__ xh2,
                                            const float* __restrict__ a_src2,
                                            const float* __restrict__ a_dst2,
                                            const float* __restrict__ bias2,
                                            float* __restrict__ out) {
    int wid  = (blockIdx.x * 256 + threadIdx.x) >> 6;
    int lane = threadIdx.x & 63;
    if (wid >= N_NODES) return;
    const int d = wid, c = lane;

    const float adh = a_dst2[d];
    float e0  = __expf(lrelu(a_src2[d] + adh));
    float x0  = (c < NCLS) ? xh2[(size_t)d * NCLS + c] : 0.f;
    float acc = e0 * x0;
    float den = e0;

    const int beg = rowptr[d], end = rowptr[d + 1];
    for (int p = beg; p < end; ++p) {
        int s = ssrc[p];
        float e = __expf(lrelu(a_src2[s] + adh));
        float xv = (c < NCLS) ? xh2[(size_t)s * NCLS + c] : 0.f;
        acc = fmaf(e, xv, acc);
        den += e;
    }
    if (c < NCLS)
        out[(size_t)d * NCLS + c] = acc / (den + 1e-16f) + bias2[c];
}

// ---------------------------------------------------------------------------
extern "C" void kernel_launch(void* const* d_in, const int* in_sizes, int n_in,
                              void* d_out, int out_size, void* d_ws, size_t ws_size,
                              hipStream_t stream) {
    const float* x    = (const float*)d_in[0];
    const float* W1   = (const float*)d_in[1];
    const float* as1w = (const float*)d_in[2];
    const float* ad1w = (const float*)d_in[3];
    const float* W2   = (const float*)d_in[4];
    const float* as2w = (const float*)d_in[5];
    const float* ad2w = (const float*)d_in[6];
    const float* b2   = (const float*)d_in[7];
    const int*   ei   = (const int*)d_in[8];
    const int*   idxp = (const int*)d_in[9];
    float* out = (float*)d_out;

    // workspace layout
    float* A    = (float*)d_ws;               // xh1 [N*64]; reused as xh2 [N*40]
    float* B    = A + (size_t)N_NODES * D1;   // h [N*64]
    float* as1  = B + (size_t)N_NODES * D1;   // [N*8]
    float* ad1  = as1 + (size_t)N_NODES * H1;
    float* as2  = ad1 + (size_t)N_NODES * H1; // [N]
    float* ad2  = as2 + N_NODES;
    int*   cnt    = (int*)(ad2 + N_NODES);    // [N]
    int*   pre    = cnt + N_NODES;            // [N]
    int*   rowptr = pre + N_NODES;            // [N+1]
    int*   wofs   = rowptr + (N_NODES + 1);   // [N]
    int*   bsum   = wofs + N_NODES;           // [128]
    int*   ssrc   = bsum + 128;               // [E]

    const int NB = (N_NODES + 1023) / 1024;   // 98 scan blocks

    // ---- CSR build ----
    hipMemsetAsync(cnt, 0, (size_t)N_NODES * sizeof(int), stream);
    k_hist<<<(N_EDGES + 255) / 256, 256, 0, stream>>>(ei, cnt);
    k_scan1<<<NB, 256, 0, stream>>>(cnt, pre, bsum);
    k_scan2<<<1, 128, 0, stream>>>(bsum, NB);
    k_scan3<<<(N_NODES + 256) / 256, 256, 0, stream>>>(pre, bsum, rowptr, wofs);
    k_scatter<<<(N_EDGES + 255) / 256, 256, 0, stream>>>(ei, wofs, ssrc);

    // ---- layer 1 ----
    gemm1<<<(N_NODES + 63) / 64, 256, 0, stream>>>(x, W1, A);
    a1k<<<(N_NODES * H1 + 255) / 256, 256, 0, stream>>>(A, as1w, ad1w, idxp, as1, ad1);
    agg1<<<(N_NODES * 64 + 255) / 256, 256, 0, stream>>>(rowptr, ssrc, A, as1, ad1, B);

    // ---- layer 2 ----
    gemm2<<<(N_NODES * NCLS + 255) / 256, 256, 0, stream>>>(B, W2, A);
    a2k<<<(N_NODES + 255) / 256, 256, 0, stream>>>(A, as2w, ad2w, idxp, as2, ad2);
    agg2<<<(N_NODES * 64 + 255) / 256, 256, 0, stream>>>(rowptr, ssrc, A, as2, ad2, b2, out);
}

// Round 3
// 682.947 us; speedup vs baseline: 1.7887x; 1.3178x over previous
//
#include <hip/hip_runtime.h>

#define N_NODES 100000
#define N_EDGES 1600000
#define F_IN    501
#define H1      8
#define C1      8
#define D1      64   // H1*C1
#define NCLS    40

typedef __attribute__((ext_vector_type(8))) short bf16x8;
typedef __attribute__((ext_vector_type(4))) float f32x4;

__device__ __forceinline__ float lrelu(float x) { return x > 0.f ? x : 0.2f * x; }

// fp32 -> bf16 round-to-nearest-even (finite inputs)
__device__ __forceinline__ unsigned short f2bf(float f) {
    unsigned u = __float_as_uint(f);
    u += 0x7FFFu + ((u >> 16) & 1u);
    return (unsigned short)(u >> 16);
}

// ---------------------------------------------------------------------------
// GEMM1 (MFMA bf16): xh1[N,64] = x[N,501] @ W1[501,64]
// block 256 (4 waves), tile 128x64, BK=32; on-the-fly fp32->bf16 staging.
// ---------------------------------------------------------------------------
__global__ __launch_bounds__(256) void gemm1(const float* __restrict__ x,
                                             const float* __restrict__ W1,
                                             float* __restrict__ xh1) {
    __shared__ __align__(16) unsigned short As[128][40]; // [row][k], 80B stride
    __shared__ __align__(16) unsigned short Bs[64][40];  // [col][k] (W1 transposed)

    const int tid  = threadIdx.x;
    const int lane = tid & 63;
    const int wave = tid >> 6;
    const int row0 = blockIdx.x * 128;
    const int lr   = lane & 15;        // fragment row/col
    const int lk   = (lane >> 4) * 8;  // fragment k offset

    f32x4 acc[2][4] = {};

    for (int k0 = 0; k0 < F_IN; k0 += 32) {
        // ---- stage A tile: 128 rows x 32 k (8 threads x 4k per row) ----
        #pragma unroll
        for (int i = 0; i < 4; ++i) {
            int r    = (tid >> 3) + i * 32;     // 0..127
            int kl   = (tid & 7) * 4;           // 0..28
            int grow = row0 + r;
            int gk   = k0 + kl;
            float v0 = 0.f, v1 = 0.f, v2 = 0.f, v3 = 0.f;
            if (grow < N_NODES) {
                const float* p = x + (size_t)grow * F_IN + gk;
                if (gk + 3 < F_IN) { v0 = p[0]; v1 = p[1]; v2 = p[2]; v3 = p[3]; }
                else {
                    if (gk + 0 < F_IN) v0 = p[0];
                    if (gk + 1 < F_IN) v1 = p[1];
                    if (gk + 2 < F_IN) v2 = p[2];
                }
            }
            ushort2* dst = (ushort2*)&As[r][kl];
            dst[0] = make_ushort2(f2bf(v0), f2bf(v1));
            dst[1] = make_ushort2(f2bf(v2), f2bf(v3));
        }
        // ---- stage W tile transposed: Bs[n][k], 32k x 64n ----
        #pragma unroll
        for (int i = 0; i < 2; ++i) {
            int e  = tid + i * 256;             // 0..511
            int n  = e & 63;
            int kl = (e >> 6) * 4;              // 0..28
            unsigned short w0, w1, w2, w3;
            {
                int gk = k0 + kl;
                w0 = (gk + 0 < F_IN) ? f2bf(W1[(size_t)(gk + 0) * D1 + n]) : 0;
                w1 = (gk + 1 < F_IN) ? f2bf(W1[(size_t)(gk + 1) * D1 + n]) : 0;
                w2 = (gk + 2 < F_IN) ? f2bf(W1[(size_t)(gk + 2) * D1 + n]) : 0;
                w3 = (gk + 3 < F_IN) ? f2bf(W1[(size_t)(gk + 3) * D1 + n]) : 0;
            }
            ushort2* dst = (ushort2*)&Bs[n][kl];
            dst[0] = make_ushort2(w0, w1);
            dst[1] = make_ushort2(w2, w3);
        }
        __syncthreads();

        bf16x8 a[2], b[4];
        #pragma unroll
        for (int m = 0; m < 2; ++m)
            a[m] = *(const bf16x8*)&As[wave * 32 + m * 16 + lr][lk];
        #pragma unroll
        for (int n = 0; n < 4; ++n)
            b[n] = *(const bf16x8*)&Bs[n * 16 + lr][lk];

        #pragma unroll
        for (int m = 0; m < 2; ++m)
            #pragma unroll
            for (int n = 0; n < 4; ++n)
                acc[m][n] = __builtin_amdgcn_mfma_f32_16x16x32_bf16(a[m], b[n], acc[m][n], 0, 0, 0);
        __syncthreads();
    }

    // epilogue: D row = (lane>>4)*4 + r, col = n*16 + (lane&15)
    #pragma unroll
    for (int m = 0; m < 2; ++m) {
        int rbase = row0 + wave * 32 + m * 16 + (lane >> 4) * 4;
        #pragma unroll
        for (int n = 0; n < 4; ++n) {
            int col = n * 16 + (lane & 15);
            #pragma unroll
            for (int r = 0; r < 4; ++r) {
                int grow = rbase + r;
                if (grow < N_NODES) xh1[(size_t)grow * D1 + col] = acc[m][n][r];
            }
        }
    }
}

// ---------------------------------------------------------------------------
// A1: per-(node,head) attention coefficients for layer 1
// ---------------------------------------------------------------------------
__global__ void a1k(const float* __restrict__ xh1,
                    const float* __restrict__ att_s, const float* __restrict__ att_d,
                    const int* __restrict__ idxp,
                    float* __restrict__ a_src, float* __restrict__ a_dst) {
    int gid = blockIdx.x * blockDim.x + threadIdx.x;
    if (gid >= N_NODES * H1) return;
    int n = gid >> 3, h = gid & 7;
    float sign = (idxp[0] == 1) ? -1.f : 1.f;
    const float* xr = xh1 + (size_t)n * D1 + h * C1;
    float ss = 0.f, sd = 0.f;
    #pragma unroll
    for (int c = 0; c < C1; ++c) {
        float v = xr[c];
        ss += v * att_s[h * C1 + c];
        sd += v * att_d[h * C1 + c];
    }
    a_src[gid] = sign * ss;
    a_dst[gid] = sign * sd;
}

// ---------------------------------------------------------------------------
// CSR build: histogram -> scan -> scatter
// ---------------------------------------------------------------------------
__global__ void k_hist(const int* __restrict__ ei, int* __restrict__ cnt) {
    int e = blockIdx.x * blockDim.x + threadIdx.x;
    if (e >= N_EDGES) return;
    atomicAdd(&cnt[ei[N_EDGES + e]], 1);
}

__global__ __launch_bounds__(256) void k_scan1(const int* __restrict__ cnt,
                                               int* __restrict__ pre,
                                               int* __restrict__ bsum) {
    __shared__ int s[256];
    int t = threadIdx.x;
    int base = blockIdx.x * 1024 + t * 4;
    int v[4], sum = 0;
    #pragma unroll
    for (int i = 0; i < 4; ++i) {
        v[i] = (base + i < N_NODES) ? cnt[base + i] : 0;
        sum += v[i];
    }
    s[t] = sum;
    __syncthreads();
    for (int off = 1; off < 256; off <<= 1) {
        int x = 0;
        if (t >= off) x = s[t - off];
        __syncthreads();
        if (t >= off) s[t] += x;
        __syncthreads();
    }
    int run = s[t] - sum;
    if (t == 255) bsum[blockIdx.x] = s[255];
    #pragma unroll
    for (int i = 0; i < 4; ++i) {
        if (base + i < N_NODES) pre[base + i] = run;
        run += v[i];
    }
}

__global__ void k_scan2(int* __restrict__ bsum, int nb) {
    __shared__ int s[128];
    int t = threadIdx.x;
    int v = (t < nb) ? bsum[t] : 0;
    s[t] = v;
    __syncthreads();
    for (int off = 1; off < 128; off <<= 1) {
        int x = 0;
        if (t >= off) x = s[t - off];
        __syncthreads();
        if (t >= off) s[t] += x;
        __syncthreads();
    }
    if (t < nb) bsum[t] = s[t] - v;
}

__global__ void k_scan3(const int* __restrict__ pre, const int* __restrict__ bsum,
                        int* __restrict__ rowptr, int* __restrict__ wofs) {
    int i = blockIdx.x * blockDim.x + threadIdx.x;
    if (i < N_NODES) {
        int r = pre[i] + bsum[i >> 10];
        rowptr[i] = r;
        wofs[i]   = r;
    } else if (i == N_NODES) {
        rowptr[N_NODES] = N_EDGES;
    }
}

__global__ void k_scatter(const int* __restrict__ ei, int* __restrict__ wofs,
                          int* __restrict__ ssrc) {
    int e = blockIdx.x * blockDim.x + threadIdx.x;
    if (e >= N_EDGES) return;
    int s = ei[e], d = ei[N_EDGES + e];
    int p = atomicAdd(&wofs[d], 1);
    ssrc[p] = s;
}

// ---------------------------------------------------------------------------
// AGG1: one wave per destination node; lane = output channel.
// ---------------------------------------------------------------------------
__global__ __launch_bounds__(256) void agg1(const int* __restrict__ rowptr,
                                            const int* __restrict__ ssrc,
                                            const float* __restrict__ xh1,
                                            const float* __restrict__ a_src,
                                            const float* __restrict__ a_dst,
                                            float* __restrict__ h) {
    int wid  = (blockIdx.x * 256 + threadIdx.x) >> 6;
    int lane = threadIdx.x & 63;
    if (wid >= N_NODES) return;
    const int d = wid, c = lane, hh = lane >> 3;

    const float adh = a_dst[d * H1 + hh];
    float e0  = __expf(lrelu(a_src[d * H1 + hh] + adh));
    float acc = e0 * xh1[(size_t)d * D1 + c];
    float den = e0;

    const int beg = rowptr[d], end = rowptr[d + 1];
    for (int p = beg; p < end; ++p) {
        int s = ssrc[p];
        float e = __expf(lrelu(a_src[s * H1 + hh] + adh));
        acc = fmaf(e, xh1[(size_t)s * D1 + c], acc);
        den += e;
    }
    float v = acc / (den + 1e-16f);
    h[(size_t)d * D1 + c] = v > 0.f ? v : (__expf(v) - 1.f);
}

// ---------------------------------------------------------------------------
// GEMM2: xh2[N,40] = h[N,64] @ W2[64,40]
// ---------------------------------------------------------------------------
__global__ void gemm2(const float* __restrict__ h,
                      const float* __restrict__ W2,
                      float* __restrict__ xh2) {
    int gid = blockIdx.x * blockDim.x + threadIdx.x;
    if (gid >= N_NODES * NCLS) return;
    int n = gid / NCLS, c = gid % NCLS;
    const float* hr = h + (size_t)n * D1;
    float s = 0.f;
    #pragma unroll
    for (int k = 0; k < D1; ++k) s = fmaf(hr[k], W2[k * NCLS + c], s);
    xh2[gid] = s;
}

// ---------------------------------------------------------------------------
// A2: per-node attention coefficients for layer 2
// ---------------------------------------------------------------------------
__global__ void a2k(const float* __restrict__ xh2,
                    const float* __restrict__ att_s2, const float* __restrict__ att_d2,
                    const int* __restrict__ idxp,
                    float* __restrict__ a_src2, float* __restrict__ a_dst2) {
    int n = blockIdx.x * blockDim.x + threadIdx.x;
    if (n >= N_NODES) return;
    float sign = (idxp[0] == 1) ? -1.f : 1.f;
    float ss = 0.f, sd = 0.f;
    #pragma unroll
    for (int c = 0; c < NCLS; ++c) {
        float v = xh2[(size_t)n * NCLS + c];
        ss += v * att_s2[c];
        sd += v * att_d2[c];
    }
    a_src2[n] = sign * ss;
    a_dst2[n] = sign * sd;
}

// ---------------------------------------------------------------------------
// AGG2: one wave per destination node; lanes 0..39 = channels. Fused bias.
// ---------------------------------------------------------------------------
__global__ __launch_bounds__(256) void agg2(const int* __restrict__ rowptr,
                                            const int* __restrict__ ssrc,
                                            const float* __restrict__ xh2,
                                            const float* __restrict__ a_src2,
                                            const float* __restrict__ a_dst2,
                                            const float* __restrict__ bias2,
                                            float* __restrict__ out) {
    int wid  = (blockIdx.x * 256 + threadIdx.x) >> 6;
    int lane = threadIdx.x & 63;
    if (wid >= N_NODES) return;
    const int d = wid, c = lane;

    const float adh = a_dst2[d];
    float e0  = __expf(lrelu(a_src2[d] + adh));
    float x0  = (c < NCLS) ? xh2[(size_t)d * NCLS + c] : 0.f;
    float acc = e0 * x0;
    float den = e0;

    const int beg = rowptr[d], end = rowptr[d + 1];
    for (int p = beg; p < end; ++p) {
        int s = ssrc[p];
        float e = __expf(lrelu(a_src2[s] + adh));
        float xv = (c < NCLS) ? xh2[(size_t)s * NCLS + c] : 0.f;
        acc = fmaf(e, xv, acc);
        den += e;
    }
    if (c < NCLS)
        out[(size_t)d * NCLS + c] = acc / (den + 1e-16f) + bias2[c];
}

// ---------------------------------------------------------------------------
extern "C" void kernel_launch(void* const* d_in, const int* in_sizes, int n_in,
                              void* d_out, int out_size, void* d_ws, size_t ws_size,
                              hipStream_t stream) {
    const float* x    = (const float*)d_in[0];
    const float* W1   = (const float*)d_in[1];
    const float* as1w = (const float*)d_in[2];
    const float* ad1w = (const float*)d_in[3];
    const float* W2   = (const float*)d_in[4];
    const float* as2w = (const float*)d_in[5];
    const float* ad2w = (const float*)d_in[6];
    const float* b2   = (const float*)d_in[7];
    const int*   ei   = (const int*)d_in[8];
    const int*   idxp = (const int*)d_in[9];
    float* out = (float*)d_out;

    // workspace layout (identical footprint to R2)
    float* A    = (float*)d_ws;               // xh1 [N*64]; reused as xh2 [N*40]
    float* B    = A + (size_t)N_NODES * D1;   // h [N*64]
    float* as1  = B + (size_t)N_NODES * D1;   // [N*8]
    float* ad1  = as1 + (size_t)N_NODES * H1;
    float* as2  = ad1 + (size_t)N_NODES * H1; // [N]
    float* ad2  = as2 + N_NODES;
    int*   cnt    = (int*)(ad2 + N_NODES);    // [N]
    int*   pre    = cnt + N_NODES;            // [N]
    int*   rowptr = pre + N_NODES;            // [N+1]
    int*   wofs   = rowptr + (N_NODES + 1);   // [N]
    int*   bsum   = wofs + N_NODES;           // [128]
    int*   ssrc   = bsum + 128;               // [E]

    const int NB = (N_NODES + 1023) / 1024;

    // ---- CSR build ----
    hipMemsetAsync(cnt, 0, (size_t)N_NODES * sizeof(int), stream);
    k_hist<<<(N_EDGES + 255) / 256, 256, 0, stream>>>(ei, cnt);
    k_scan1<<<NB, 256, 0, stream>>>(cnt, pre, bsum);
    k_scan2<<<1, 128, 0, stream>>>(bsum, NB);
    k_scan3<<<(N_NODES + 256) / 256, 256, 0, stream>>>(pre, bsum, rowptr, wofs);
    k_scatter<<<(N_EDGES + 255) / 256, 256, 0, stream>>>(ei, wofs, ssrc);

    // ---- layer 1 ----
    gemm1<<<(N_NODES + 127) / 128, 256, 0, stream>>>(x, W1, A);
    a1k<<<(N_NODES * H1 + 255) / 256, 256, 0, stream>>>(A, as1w, ad1w, idxp, as1, ad1);
    agg1<<<(N_NODES * 64 + 255) / 256, 256, 0, stream>>>(rowptr, ssrc, A, as1, ad1, B);

    // ---- layer 2 ----
    gemm2<<<(N_NODES * NCLS + 255) / 256, 256, 0, stream>>>(B, W2, A);
    a2k<<<(N_NODES + 255) / 256, 256, 0, stream>>>(A, as2w, ad2w, idxp, as2, ad2);
    agg2<<<(N_NODES * 64 + 255) / 256, 256, 0, stream>>>(rowptr, ssrc, A, as2, ad2, b2, out);
}

// Round 4
// 553.349 us; speedup vs baseline: 2.2076x; 1.2342x over previous
//
#include <hip/hip_runtime.h>

#define N_NODES 100000
#define N_EDGES 1600000
#define F_IN    501
#define H1      8
#define C1      8
#define D1      64   // H1*C1
#define NCLS    40

typedef __attribute__((ext_vector_type(8))) short bf16x8;
typedef __attribute__((ext_vector_type(4))) float f32x4;

__device__ __forceinline__ float lrelu(float x) { return x > 0.f ? x : 0.2f * x; }

// fp32 -> bf16 round-to-nearest-even (finite inputs)
__device__ __forceinline__ unsigned short f2bf(float f) {
    unsigned u = __float_as_uint(f);
    u += 0x7FFFu + ((u >> 16) & 1u);
    return (unsigned short)(u >> 16);
}
__device__ __forceinline__ float bf2f(unsigned short u) {
    return __uint_as_float(((unsigned)u) << 16);
}

// ---------------------------------------------------------------------------
// GEMM1 (MFMA bf16): xh1b[N,64] = bf16( x[N,501] @ W1[501,64] )
// block 256 (4 waves), tile 128x64, BK=32; on-the-fly fp32->bf16 staging.
// ---------------------------------------------------------------------------
__global__ __launch_bounds__(256) void gemm1(const float* __restrict__ x,
                                             const float* __restrict__ W1,
                                             unsigned short* __restrict__ xh1b) {
    __shared__ __align__(16) unsigned short As[128][40]; // [row][k], 80B stride
    __shared__ __align__(16) unsigned short Bs[64][40];  // [col][k] (W1 transposed)

    const int tid  = threadIdx.x;
    const int lane = tid & 63;
    const int wave = tid >> 6;
    const int row0 = blockIdx.x * 128;
    const int lr   = lane & 15;
    const int lk   = (lane >> 4) * 8;

    f32x4 acc[2][4] = {};

    for (int k0 = 0; k0 < F_IN; k0 += 32) {
        #pragma unroll
        for (int i = 0; i < 4; ++i) {
            int r    = (tid >> 3) + i * 32;
            int kl   = (tid & 7) * 4;
            int grow = row0 + r;
            int gk   = k0 + kl;
            float v0 = 0.f, v1 = 0.f, v2 = 0.f, v3 = 0.f;
            if (grow < N_NODES) {
                const float* p = x + (size_t)grow * F_IN + gk;
                if (gk + 3 < F_IN) { v0 = p[0]; v1 = p[1]; v2 = p[2]; v3 = p[3]; }
                else {
                    if (gk + 0 < F_IN) v0 = p[0];
                    if (gk + 1 < F_IN) v1 = p[1];
                    if (gk + 2 < F_IN) v2 = p[2];
                }
            }
            ushort2* dst = (ushort2*)&As[r][kl];
            dst[0] = make_ushort2(f2bf(v0), f2bf(v1));
            dst[1] = make_ushort2(f2bf(v2), f2bf(v3));
        }
        #pragma unroll
        for (int i = 0; i < 2; ++i) {
            int e  = tid + i * 256;
            int n  = e & 63;
            int kl = (e >> 6) * 4;
            int gk = k0 + kl;
            unsigned short w0 = (gk + 0 < F_IN) ? f2bf(W1[(size_t)(gk + 0) * D1 + n]) : 0;
            unsigned short w1 = (gk + 1 < F_IN) ? f2bf(W1[(size_t)(gk + 1) * D1 + n]) : 0;
            unsigned short w2 = (gk + 2 < F_IN) ? f2bf(W1[(size_t)(gk + 2) * D1 + n]) : 0;
            unsigned short w3 = (gk + 3 < F_IN) ? f2bf(W1[(size_t)(gk + 3) * D1 + n]) : 0;
            ushort2* dst = (ushort2*)&Bs[n][kl];
            dst[0] = make_ushort2(w0, w1);
            dst[1] = make_ushort2(w2, w3);
        }
        __syncthreads();

        bf16x8 a[2], b[4];
        #pragma unroll
        for (int m = 0; m < 2; ++m)
            a[m] = *(const bf16x8*)&As[wave * 32 + m * 16 + lr][lk];
        #pragma unroll
        for (int n = 0; n < 4; ++n)
            b[n] = *(const bf16x8*)&Bs[n * 16 + lr][lk];

        #pragma unroll
        for (int m = 0; m < 2; ++m)
            #pragma unroll
            for (int n = 0; n < 4; ++n)
                acc[m][n] = __builtin_amdgcn_mfma_f32_16x16x32_bf16(a[m], b[n], acc[m][n], 0, 0, 0);
        __syncthreads();
    }

    #pragma unroll
    for (int m = 0; m < 2; ++m) {
        int rbase = row0 + wave * 32 + m * 16 + (lane >> 4) * 4;
        #pragma unroll
        for (int n = 0; n < 4; ++n) {
            int col = n * 16 + (lane & 15);
            #pragma unroll
            for (int r = 0; r < 4; ++r) {
                int grow = rbase + r;
                if (grow < N_NODES) xh1b[(size_t)grow * D1 + col] = f2bf(acc[m][n][r]);
            }
        }
    }
}

// ---------------------------------------------------------------------------
// A1: per-(node,head) attention coefficients for layer 1 (bf16 features)
// ---------------------------------------------------------------------------
__global__ void a1k(const unsigned short* __restrict__ xh1b,
                    const float* __restrict__ att_s, const float* __restrict__ att_d,
                    const int* __restrict__ idxp,
                    float* __restrict__ a_src, float* __restrict__ a_dst) {
    int gid = blockIdx.x * blockDim.x + threadIdx.x;
    if (gid >= N_NODES * H1) return;
    int n = gid >> 3, h = gid & 7;
    float sign = (idxp[0] == 1) ? -1.f : 1.f;
    uint4 u = *(const uint4*)(xh1b + (size_t)n * D1 + h * C1);   // 8 bf16
    float v[8];
    v[0] = bf2f((unsigned short)(u.x & 0xffff)); v[1] = bf2f((unsigned short)(u.x >> 16));
    v[2] = bf2f((unsigned short)(u.y & 0xffff)); v[3] = bf2f((unsigned short)(u.y >> 16));
    v[4] = bf2f((unsigned short)(u.z & 0xffff)); v[5] = bf2f((unsigned short)(u.z >> 16));
    v[6] = bf2f((unsigned short)(u.w & 0xffff)); v[7] = bf2f((unsigned short)(u.w >> 16));
    float ss = 0.f, sd = 0.f;
    #pragma unroll
    for (int c = 0; c < C1; ++c) {
        ss += v[c] * att_s[h * C1 + c];
        sd += v[c] * att_d[h * C1 + c];
    }
    a_src[gid] = sign * ss;
    a_dst[gid] = sign * sd;
}

// ---------------------------------------------------------------------------
// CSR build: histogram -> scan -> scatter
// ---------------------------------------------------------------------------
__global__ void k_hist(const int* __restrict__ ei, int* __restrict__ cnt) {
    int e = blockIdx.x * blockDim.x + threadIdx.x;
    if (e >= N_EDGES) return;
    atomicAdd(&cnt[ei[N_EDGES + e]], 1);
}

__global__ __launch_bounds__(256) void k_scan1(const int* __restrict__ cnt,
                                               int* __restrict__ pre,
                                               int* __restrict__ bsum) {
    __shared__ int s[256];
    int t = threadIdx.x;
    int base = blockIdx.x * 1024 + t * 4;
    int v[4], sum = 0;
    #pragma unroll
    for (int i = 0; i < 4; ++i) {
        v[i] = (base + i < N_NODES) ? cnt[base + i] : 0;
        sum += v[i];
    }
    s[t] = sum;
    __syncthreads();
    for (int off = 1; off < 256; off <<= 1) {
        int x = 0;
        if (t >= off) x = s[t - off];
        __syncthreads();
        if (t >= off) s[t] += x;
        __syncthreads();
    }
    int run = s[t] - sum;
    if (t == 255) bsum[blockIdx.x] = s[255];
    #pragma unroll
    for (int i = 0; i < 4; ++i) {
        if (base + i < N_NODES) pre[base + i] = run;
        run += v[i];
    }
}

__global__ void k_scan2(int* __restrict__ bsum, int nb) {
    __shared__ int s[128];
    int t = threadIdx.x;
    int v = (t < nb) ? bsum[t] : 0;
    s[t] = v;
    __syncthreads();
    for (int off = 1; off < 128; off <<= 1) {
        int x = 0;
        if (t >= off) x = s[t - off];
        __syncthreads();
        if (t >= off) s[t] += x;
        __syncthreads();
    }
    if (t < nb) bsum[t] = s[t] - v;
}

__global__ void k_scan3(const int* __restrict__ pre, const int* __restrict__ bsum,
                        int* __restrict__ rowptr, int* __restrict__ wofs) {
    int i = blockIdx.x * blockDim.x + threadIdx.x;
    if (i < N_NODES) {
        int r = pre[i] + bsum[i >> 10];
        rowptr[i] = r;
        wofs[i]   = r;
    } else if (i == N_NODES) {
        rowptr[N_NODES] = N_EDGES;
    }
}

__global__ void k_scatter(const int* __restrict__ ei, int* __restrict__ wofs,
                          int* __restrict__ ssrc) {
    int e = blockIdx.x * blockDim.x + threadIdx.x;
    if (e >= N_EDGES) return;
    int s = ei[e], d = ei[N_EDGES + e];
    int p = atomicAdd(&wofs[d], 1);
    ssrc[p] = s;
}

// ---------------------------------------------------------------------------
// AGG1: one wave per destination; 2 edges in flight (half-waves).
// Lane li (0..31) covers channels (2li, 2li+1); head = li>>2.
// ---------------------------------------------------------------------------
__global__ __launch_bounds__(256) void agg1(const int* __restrict__ rowptr,
                                            const int* __restrict__ ssrc,
                                            const unsigned short* __restrict__ xh1b,
                                            const float* __restrict__ a_src,
                                            const float* __restrict__ a_dst,
                                            unsigned short* __restrict__ hb) {
    int wid  = (blockIdx.x * 256 + threadIdx.x) >> 6;
    int lane = threadIdx.x & 63;
    if (wid >= N_NODES) return;
    const int d    = wid;
    const int li   = lane & 31;
    const int half = lane >> 5;
    const int hh   = li >> 2;

    const float adh = a_dst[d * H1 + hh];
    float acc0 = 0.f, acc1 = 0.f, den = 0.f;
    if (half == 0) {
        float e0 = __expf(lrelu(a_src[d * H1 + hh] + adh));
        ushort2 v = *(const ushort2*)&xh1b[(size_t)d * D1 + (li << 1)];
        acc0 = e0 * bf2f(v.x);
        acc1 = e0 * bf2f(v.y);
        den  = e0;
    }

    const int beg = rowptr[d], end = rowptr[d + 1];
    for (int p = beg + half; p < end; p += 2) {
        int s = ssrc[p];
        float as = a_src[s * H1 + hh];
        ushort2 v = *(const ushort2*)&xh1b[(size_t)s * D1 + (li << 1)];
        float e = __expf(lrelu(as + adh));
        acc0 = fmaf(e, bf2f(v.x), acc0);
        acc1 = fmaf(e, bf2f(v.y), acc1);
        den += e;
    }

    acc0 += __shfl_xor(acc0, 32);
    acc1 += __shfl_xor(acc1, 32);
    den  += __shfl_xor(den, 32);

    if (half == 0) {
        float inv = 1.f / (den + 1e-16f);
        float v0 = acc0 * inv, v1 = acc1 * inv;
        v0 = v0 > 0.f ? v0 : (__expf(v0) - 1.f);
        v1 = v1 > 0.f ? v1 : (__expf(v1) - 1.f);
        *(ushort2*)&hb[(size_t)d * D1 + (li << 1)] = make_ushort2(f2bf(v0), f2bf(v1));
    }
}

// ---------------------------------------------------------------------------
// GEMM2: xh2b[N,40] = bf16( h[N,64] @ W2[64,40] )
// ---------------------------------------------------------------------------
__global__ void gemm2(const unsigned short* __restrict__ hb,
                      const float* __restrict__ W2,
                      unsigned short* __restrict__ xh2b) {
    int gid = blockIdx.x * blockDim.x + threadIdx.x;
    if (gid >= N_NODES * NCLS) return;
    int n = gid / NCLS, c = gid % NCLS;
    const uint4* hr = (const uint4*)(hb + (size_t)n * D1);
    float s = 0.f;
    #pragma unroll
    for (int q = 0; q < 8; ++q) {
        uint4 u = hr[q];
        int k = q * 8;
        s = fmaf(bf2f((unsigned short)(u.x & 0xffff)), W2[(k + 0) * NCLS + c], s);
        s = fmaf(bf2f((unsigned short)(u.x >> 16)),    W2[(k + 1) * NCLS + c], s);
        s = fmaf(bf2f((unsigned short)(u.y & 0xffff)), W2[(k + 2) * NCLS + c], s);
        s = fmaf(bf2f((unsigned short)(u.y >> 16)),    W2[(k + 3) * NCLS + c], s);
        s = fmaf(bf2f((unsigned short)(u.z & 0xffff)), W2[(k + 4) * NCLS + c], s);
        s = fmaf(bf2f((unsigned short)(u.z >> 16)),    W2[(k + 5) * NCLS + c], s);
        s = fmaf(bf2f((unsigned short)(u.w & 0xffff)), W2[(k + 6) * NCLS + c], s);
        s = fmaf(bf2f((unsigned short)(u.w >> 16)),    W2[(k + 7) * NCLS + c], s);
    }
    xh2b[gid] = f2bf(s);
}

// ---------------------------------------------------------------------------
// A2: per-node attention coefficients for layer 2 (bf16 features)
// ---------------------------------------------------------------------------
__global__ void a2k(const unsigned short* __restrict__ xh2b,
                    const float* __restrict__ att_s2, const float* __restrict__ att_d2,
                    const int* __restrict__ idxp,
                    float* __restrict__ a_src2, float* __restrict__ a_dst2) {
    int n = blockIdx.x * blockDim.x + threadIdx.x;
    if (n >= N_NODES) return;
    float sign = (idxp[0] == 1) ? -1.f : 1.f;
    const uint4* xr = (const uint4*)(xh2b + (size_t)n * NCLS);
    float ss = 0.f, sd = 0.f;
    #pragma unroll
    for (int q = 0; q < 5; ++q) {
        uint4 u = xr[q];
        int k = q * 8;
        float v[8];
        v[0] = bf2f((unsigned short)(u.x & 0xffff)); v[1] = bf2f((unsigned short)(u.x >> 16));
        v[2] = bf2f((unsigned short)(u.y & 0xffff)); v[3] = bf2f((unsigned short)(u.y >> 16));
        v[4] = bf2f((unsigned short)(u.z & 0xffff)); v[5] = bf2f((unsigned short)(u.z >> 16));
        v[6] = bf2f((unsigned short)(u.w & 0xffff)); v[7] = bf2f((unsigned short)(u.w >> 16));
        #pragma unroll
        for (int j = 0; j < 8; ++j) {
            ss += v[j] * att_s2[k + j];
            sd += v[j] * att_d2[k + j];
        }
    }
    a_src2[n] = sign * ss;
    a_dst2[n] = sign * sd;
}

// ---------------------------------------------------------------------------
// AGG2: one wave per destination; 2 edges in flight; lanes li<20 carry
// channels (2li, 2li+1). Fused self-loop, normalize, bias -> out (fp32).
// ---------------------------------------------------------------------------
__global__ __launch_bounds__(256) void agg2(const int* __restrict__ rowptr,
                                            const int* __restrict__ ssrc,
                                            const unsigned short* __restrict__ xh2b,
                                            const float* __restrict__ a_src2,
                                            const float* __restrict__ a_dst2,
                                            const float* __restrict__ bias2,
                                            float* __restrict__ out) {
    int wid  = (blockIdx.x * 256 + threadIdx.x) >> 6;
    int lane = threadIdx.x & 63;
    if (wid >= N_NODES) return;
    const int d    = wid;
    const int li   = lane & 31;
    const int half = lane >> 5;
    const bool act = li < (NCLS / 2);

    const float adh = a_dst2[d];
    float acc0 = 0.f, acc1 = 0.f, den = 0.f;
    if (half == 0) {
        float e0 = __expf(lrelu(a_src2[d] + adh));
        if (act) {
            ushort2 v = *(const ushort2*)&xh2b[(size_t)d * NCLS + (li << 1)];
            acc0 = e0 * bf2f(v.x);
            acc1 = e0 * bf2f(v.y);
        }
        den = e0;
    }

    const int beg = rowptr[d], end = rowptr[d + 1];
    for (int p = beg + half; p < end; p += 2) {
        int s = ssrc[p];
        float as = a_src2[s];
        float e = __expf(lrelu(as + adh));
        if (act) {
            ushort2 v = *(const ushort2*)&xh2b[(size_t)s * NCLS + (li << 1)];
            acc0 = fmaf(e, bf2f(v.x), acc0);
            acc1 = fmaf(e, bf2f(v.y), acc1);
        }
        den += e;
    }

    acc0 += __shfl_xor(acc0, 32);
    acc1 += __shfl_xor(acc1, 32);
    den  += __shfl_xor(den, 32);

    if (half == 0 && act) {
        float inv = 1.f / (den + 1e-16f);
        float2 r;
        r.x = acc0 * inv + bias2[li * 2 + 0];
        r.y = acc1 * inv + bias2[li * 2 + 1];
        *(float2*)&out[(size_t)d * NCLS + (li << 1)] = r;
    }
}

// ---------------------------------------------------------------------------
extern "C" void kernel_launch(void* const* d_in, const int* in_sizes, int n_in,
                              void* d_out, int out_size, void* d_ws, size_t ws_size,
                              hipStream_t stream) {
    const float* x    = (const float*)d_in[0];
    const float* W1   = (const float*)d_in[1];
    const float* as1w = (const float*)d_in[2];
    const float* ad1w = (const float*)d_in[3];
    const float* W2   = (const float*)d_in[4];
    const float* as2w = (const float*)d_in[5];
    const float* ad2w = (const float*)d_in[6];
    const float* b2   = (const float*)d_in[7];
    const int*   ei   = (const int*)d_in[8];
    const int*   idxp = (const int*)d_in[9];
    float* out = (float*)d_out;

    // workspace layout
    unsigned short* xh1b = (unsigned short*)d_ws;        // [N*64] bf16
    unsigned short* hb   = xh1b + (size_t)N_NODES * D1;  // [N*64] bf16
    unsigned short* xh2b = hb + (size_t)N_NODES * D1;    // [N*40] bf16
    float* as1 = (float*)(xh2b + (size_t)N_NODES * NCLS);
    float* ad1 = as1 + (size_t)N_NODES * H1;
    float* as2 = ad1 + (size_t)N_NODES * H1;             // [N]
    float* ad2 = as2 + N_NODES;
    int*   cnt    = (int*)(ad2 + N_NODES);               // [N]
    int*   pre    = cnt + N_NODES;                       // [N]
    int*   rowptr = pre + N_NODES;                       // [N+1]
    int*   wofs   = rowptr + (N_NODES + 1);              // [N]
    int*   bsum   = wofs + N_NODES;                      // [128]
    int*   ssrc   = bsum + 128;                          // [E]

    const int NB = (N_NODES + 1023) / 1024;

    // ---- CSR build ----
    hipMemsetAsync(cnt, 0, (size_t)N_NODES * sizeof(int), stream);
    k_hist<<<(N_EDGES + 255) / 256, 256, 0, stream>>>(ei, cnt);
    k_scan1<<<NB, 256, 0, stream>>>(cnt, pre, bsum);
    k_scan2<<<1, 128, 0, stream>>>(bsum, NB);
    k_scan3<<<(N_NODES + 256) / 256, 256, 0, stream>>>(pre, bsum, rowptr, wofs);
    k_scatter<<<(N_EDGES + 255) / 256, 256, 0, stream>>>(ei, wofs, ssrc);

    // ---- layer 1 ----
    gemm1<<<(N_NODES + 127) / 128, 256, 0, stream>>>(x, W1, xh1b);
    a1k<<<(N_NODES * H1 + 255) / 256, 256, 0, stream>>>(xh1b, as1w, ad1w, idxp, as1, ad1);
    agg1<<<(N_NODES * 64 + 255) / 256, 256, 0, stream>>>(rowptr, ssrc, xh1b, as1, ad1, hb);

    // ---- layer 2 ----
    gemm2<<<(N_NODES * NCLS + 255) / 256, 256, 0, stream>>>(hb, W2, xh2b);
    a2k<<<(N_NODES + 255) / 256, 256, 0, stream>>>(xh2b, as2w, ad2w, idxp, as2, ad2);
    agg2<<<(N_NODES * 64 + 255) / 256, 256, 0, stream>>>(rowptr, ssrc, xh2b, as2, ad2, b2, out);
}